// Round 14
// baseline (197.124 us; speedup 1.0000x reference)
//
#include <hip/hip_runtime.h>
#include <math.h>

#define BN_EPS 1e-5f

constexpr int B  = 4;
constexpr int C  = 256;
constexpr int HW = 4096;   // 64*64
constexpr int CK = 64;
constexpr int CV = 256;
constexpr int CO = 320;    // CK + CV
constexpr int CHG = 2;     // channel groups in attn (128 ch each)
constexpr int JS  = 2;     // j-splits (partials + atomic merge)

typedef short bf16x8 __attribute__((ext_vector_type(8)));
typedef float f32x4  __attribute__((ext_vector_type(4)));
typedef unsigned uint32x4 __attribute__((ext_vector_type(4)));

__device__ __forceinline__ ushort f2bf(float f) {
    unsigned u = __float_as_uint(f);
    u += 0x7FFFu + ((u >> 16) & 1u);      // round to nearest even
    return (ushort)(u >> 16);
}

// packed f32x2 -> bf16x2 (RNE), one VALU inst (T12 primitive)
__device__ __forceinline__ unsigned cvtpk_bf16(float lo, float hi) {
    unsigned r;
    asm("v_cvt_pk_bf16_f32 %0, %1, %2" : "=v"(r) : "v"(lo), "v"(hi));
    return r;
}

// byte-XOR swizzles (applied identically to pre-swizzled global source and
// LDS read -> involution, bijective within each 128-B row)
__device__ __forceinline__ int swzk(int r) {
    return (((r & 3) | ((((r >> 2) ^ (r >> 3)) & 1) << 2)) << 4);
}
__device__ __forceinline__ int swzv(int r) { return (r & 7) << 4; }

__device__ __forceinline__ void gload_lds16(const void* g, void* l) {
    __builtin_amdgcn_global_load_lds(
        (const __attribute__((address_space(1))) unsigned*)g,
        (__attribute__((address_space(3))) unsigned*)l, 16, 0, 0);
}

// ---------------------------------------------------------------------------
// Kernel 0: fold BN into Wk (row-scale), emit bf16 weights PRE-PACKED in
// kv_gemm's MFMA fragment order. Also zero-inits Mx.
// ---------------------------------------------------------------------------
__global__ __launch_bounds__(256) void wprep(
    const float* __restrict__ Wk, const float* __restrict__ bk,
    const float* __restrict__ gamma, const float* __restrict__ beta,
    const float* __restrict__ mean,  const float* __restrict__ var,
    const float* __restrict__ Wv, const float* __restrict__ bv,
    ushort* __restrict__ Wq, float* __restrict__ bq, unsigned* __restrict__ Mx)
{
    const int co = blockIdx.x;
    const int c  = threadIdx.x;
    if (co < B && c == 0) Mx[co] = 0u;
    float w;
    if (co < CK) {
        float inv = gamma[co] * rsqrtf(var[co] + BN_EPS);
        w = Wk[co * C + c] * inv;
        if (c == 0) bq[co] = bk[co] * inv + (beta[co] - mean[co] * inv);
    } else {
        w = Wv[(co - CK) * C + c];
        if (c == 0) bq[co] = bv[co - CK];
    }
    // co = wv*80 + mi*16 + col ; c = ks*32 + q*8 + e
    const int wv  = co / 80, rem = co % 80;
    const int mi  = rem / 16, colw = rem % 16;
    const int ks  = c >> 5, qw = (c >> 3) & 3, e = c & 7;
    Wq[((((((wv * 8 + ks) * 5 + mi) * 4 + qw) * 16 + colw)) << 3) + e] = f2bf(w);
}

// ---------------------------------------------------------------------------
// Kernel 1: KV projection as MFMA GEMM + fused K-norms. UNCHANGED from R13
// (passed; kv_gemm proven non-dominant).
// ---------------------------------------------------------------------------
__global__ __launch_bounds__(256) void kv_gemm(
    const float* __restrict__ x, const ushort* __restrict__ Wq,
    const float* __restrict__ bq,
    ushort* __restrict__ Kbuf, ushort* __restrict__ Vbuf,
    float* __restrict__ mb, unsigned* __restrict__ Mx)
{
    __shared__ __align__(16) ushort xt[32][C + 8];   // [hw][c] bf16, pad 8

    const int t    = threadIdx.x;
    const int lane = t & 63;
    const int wv   = t >> 6;
    const int q    = lane >> 4;
    const int col  = lane & 15;
    const int hw0  = blockIdx.x * 32;
    const int b    = blockIdx.y;

    const float* xb = x + (size_t)b * C * HW;

    // stage x tile: strided dword loads -> pack bf16x4 -> b64 LDS write
    {
        const int cq  = (t >> 5) * 4;    // 0,4,...,28
        const int hwo = t & 31;
#pragma unroll
        for (int pass = 0; pass < 8; pass++) {
            const int c0 = pass * 32;
            float a0 = xb[(size_t)(c0 + cq + 0) * HW + hw0 + hwo];
            float a1 = xb[(size_t)(c0 + cq + 1) * HW + hw0 + hwo];
            float a2 = xb[(size_t)(c0 + cq + 2) * HW + hw0 + hwo];
            float a3 = xb[(size_t)(c0 + cq + 3) * HW + hw0 + hwo];
            ushort4 u = make_ushort4(f2bf(a0), f2bf(a1), f2bf(a2), f2bf(a3));
            *(ushort4*)&xt[hwo][c0 + cq] = u;
        }
    }
    __syncthreads();

    f32x4 acc[5][2];
#pragma unroll
    for (int mi = 0; mi < 5; mi++)
#pragma unroll
        for (int nt = 0; nt < 2; nt++)
            acc[mi][nt] = (f32x4){0.f, 0.f, 0.f, 0.f};

#pragma unroll
    for (int ks = 0; ks < 8; ks++) {
        bf16x8 av[5], bvv[2];
#pragma unroll
        for (int mi = 0; mi < 5; mi++)
            av[mi] = *(const bf16x8*)(Wq + ((size_t)((wv * 8 + ks) * 5 + mi) << 9) + lane * 8);
#pragma unroll
        for (int nt = 0; nt < 2; nt++)
            bvv[nt] = *(const bf16x8*)&xt[nt * 16 + col][ks * 32 + q * 8];
#pragma unroll
        for (int mi = 0; mi < 5; mi++)
#pragma unroll
            for (int nt = 0; nt < 2; nt++)
                acc[mi][nt] = __builtin_amdgcn_mfma_f32_16x16x32_bf16(bvv[nt], av[mi], acc[mi][nt], 0, 0, 0);
    }

    // D: row m = q*4+r -> hw = hw0 + nt*16 + q*4 + r ; col n -> co = cot+col
    float ssq[2][4] = {{0.f,0.f,0.f,0.f},{0.f,0.f,0.f,0.f}};
#pragma unroll
    for (int mi = 0; mi < 5; mi++) {
        const int cot = wv * 80 + mi * 16;
        const float bi = bq[cot + col];
#pragma unroll
        for (int nt = 0; nt < 2; nt++) {
            const int hwr = hw0 + nt * 16 + q * 4;
            float v0 = acc[mi][nt][0] + bi;
            float v1 = acc[mi][nt][1] + bi;
            float v2 = acc[mi][nt][2] + bi;
            float v3 = acc[mi][nt][3] + bi;
            if (cot < CK) {           // K: [hw][ck] layout, scalar stores
                const int ck = cot + col;
                Kbuf[((size_t)b * HW + hwr + 0) * CK + ck] = f2bf(v0);
                Kbuf[((size_t)b * HW + hwr + 1) * CK + ck] = f2bf(v1);
                Kbuf[((size_t)b * HW + hwr + 2) * CK + ck] = f2bf(v2);
                Kbuf[((size_t)b * HW + hwr + 3) * CK + ck] = f2bf(v3);
                ssq[nt][0] += v0 * v0; ssq[nt][1] += v1 * v1;
                ssq[nt][2] += v2 * v2; ssq[nt][3] += v3 * v3;
            } else {                  // V: [cv][hw] layout, ushort4 store
                const int cv = cot - CK + col;
                ushort4 vv = make_ushort4(f2bf(v0), f2bf(v1), f2bf(v2), f2bf(v3));
                *(ushort4*)&Vbuf[((size_t)b * CV + cv) * HW + hwr] = vv;
            }
        }
    }

    if (wv == 0) {   // wave 0 computed all K tiles: finish row norms
        float mxn = 0.f;
#pragma unroll
        for (int nt = 0; nt < 2; nt++) {
#pragma unroll
            for (int off = 1; off <= 8; off <<= 1)
#pragma unroll
                for (int r = 0; r < 4; r++)
                    ssq[nt][r] += __shfl_xor(ssq[nt][r], off, 64);
            float4 nr = make_float4(sqrtf(ssq[nt][0]), sqrtf(ssq[nt][1]),
                                    sqrtf(ssq[nt][2]), sqrtf(ssq[nt][3]));
            if (col == 0)
                *(float4*)&mb[(size_t)b * HW + hw0 + nt * 16 + q * 4] = nr;
            mxn = fmaxf(mxn, fmaxf(fmaxf(nr.x, nr.y), fmaxf(nr.z, nr.w)));
        }
#pragma unroll
        for (int off = 1; off <= 32; off <<= 1)
            mxn = fmaxf(mxn, __shfl_xor(mxn, off, 64));
        if (t == 0) atomicMax(Mx + b, __float_as_uint(mxn));
    }
}

// ---------------------------------------------------------------------------
// Kernel 2: MFMA flash attention. R18: R15 body (best verified, 82.0 us,
// 68 VGPR) + JS=2 j-split -> grid 1024 blocks so 3 blocks/CU can be
// RESIDENT (48 KB LDS x 3 = 144 < 160 KB) = 3 waves/SIMD.
//
// Rationale: all pipes <50%, occupancy 20.5% (2 waves/SIMD); R11-R17 showed
// time tracks the per-wave serial stream with ~2.5x stall factor that no
// serial-stream optimization removed -> latency-bound at low TLP. Every
// prior grid was exactly 512 = 2 blocks/CU; this is the first TLP increase.
// Cost: j-partials -> atomicAdd O/L + norm_out (proven R7/R14 epilogue).
// ---------------------------------------------------------------------------
__global__ __launch_bounds__(256, 2) void attn_kernel(
    const ushort* __restrict__ Kbuf, const ushort* __restrict__ Vbuf,
    const float* __restrict__ mb, const unsigned* __restrict__ Mx,
    float* __restrict__ out, float* __restrict__ Lbuf)
{
    __shared__ __align__(16) ushort Kt[2][64 * 64];    // 8 KB per buf
    __shared__ __align__(16) ushort Vt[2][128 * 64];   // 16 KB per buf

    const int t    = threadIdx.x;
    const int lane = t & 63;
    const int wv   = t >> 6;          // 0..3 : i-group within block
    const int q    = lane >> 4;       // quad 0..3
    const int col  = lane & 15;

    // --- XCD-partition remap (bijective on the 1024-block grid) ---
    // 16 combos (chg,js,b); 2 per XCD -> K/V halves ~1.5 MB < 4 MB L2.
    const unsigned lin = blockIdx.x + 64u * (blockIdx.y + 4u * blockIdx.z);
    const int xcd   = lin & 7;
    const int s_    = lin >> 3;              // 0..127
    const int combo = xcd + 8 * (s_ >> 6);   // 0..15
    const int i0g   = (s_ & 63) * 64;
    const int chg   = combo & 1;
    const int js    = (combo >> 1) & 1;
    const int b     = combo >> 2;            // 0..3

    const int jbase = js * (HW / JS);
    const int iw    = wv * 16 + col;         // local i row (0..63)
    const int jperm = (col >> 2) * 8 + (col & 3);  // j-row permutation base

    const ushort* Kb = Kbuf + (size_t)b * HW * CK;
    const ushort* Vb = Vbuf + (size_t)b * CV * HW;
    const int cbase = chg * 128;

    // Q B-frags: B[k=ck][n=i], n = col -> i = i0g + iw (one-time scattered)
    bf16x8 qa[2];
#pragma unroll
    for (int k = 0; k < 2; k++)
        qa[k] = *(const bf16x8*)(Kb + (size_t)(i0g + iw) * CK + k * 32 + q * 8);

    // per-row exp bound (Cauchy-Schwarz): one scalar per lane
    const float Mxf = __uint_as_float(Mx[b]);
    const float m_val = mb[(size_t)b * HW + i0g + iw] * Mxf;

    f32x4 Oacc[8];
#pragma unroll
    for (int mt = 0; mt < 8; mt++)
        Oacc[mt] = (f32x4){0.f, 0.f, 0.f, 0.f};

    float l_acc = 0.f;
    const f32x4 zf = (f32x4){0.f, 0.f, 0.f, 0.f};

    // ---- staging: K tile 8 KB (2 chunks/wave), V tile 16 KB (4 chunks/wave)
#define STAGE(BUF, JN)                                                         \
    {                                                                          \
        const int jn_s = (JN);                                                 \
        _Pragma("unroll")                                                      \
        for (int p = 0; p < 2; p++) {                                          \
            int off = (wv * 2 + p) * 1024 + lane * 16;                         \
            int r = off >> 7, cb = off & 127;                                  \
            const char* g = (const char*)Kb + (size_t)(jn_s + r) * 128         \
                            + (cb ^ swzk(r));                                  \
            gload_lds16(g, (char*)&Kt[BUF][0] + off);                          \
        }                                                                      \
        _Pragma("unroll")                                                      \
        for (int p = 0; p < 4; p++) {                                          \
            int off = (wv * 4 + p) * 1024 + lane * 16;                         \
            int r = off >> 7, cb = off & 127;                                  \
            const char* g = (const char*)Vb                                    \
                            + ((size_t)(cbase + r) * HW + jn_s) * 2            \
                            + (cb ^ swzv(r));                                  \
            gload_lds16(g, (char*)&Vt[BUF][0] + off);                          \
        }                                                                      \
    }

    // prologue: stage tile 0 into buf 0
    STAGE(0, jbase);
    __syncthreads();

    int cur = 0;
    for (int jo = 0; jo < HW / JS; jo += 64) {
        // issue next tile's staging first (full-tile latency window)
        STAGE(cur ^ 1, jbase + ((jo + 64) & (HW / JS - 1)));

        const char* KtB = (const char*)&Kt[cur][0];
        const char* VtB = (const char*)&Vt[cur][0];

        // S^T = mfma(K, Q): K A-frags from LDS (jperm rows, swizzled)
        f32x4 S[4];
        __builtin_amdgcn_s_setprio(1);
#pragma unroll
        for (int nt = 0; nt < 4; nt++) {
            const int jr = jperm + (nt >> 1) * 32 + (nt & 1) * 4;
            bf16x8 k0 = *(const bf16x8*)(KtB + jr * 128 + ((q * 16) ^ swzk(jr)));
            bf16x8 k1 = *(const bf16x8*)(KtB + jr * 128 + ((64 + q * 16) ^ swzk(jr)));
            S[nt] = __builtin_amdgcn_mfma_f32_16x16x32_bf16(k0, qa[0], zf, 0, 0, 0);
            S[nt] = __builtin_amdgcn_mfma_f32_16x16x32_bf16(k1, qa[1], S[nt], 0, 0, 0);
        }
        __builtin_amdgcn_s_setprio(0);

        // exp + pack into PV B-fragments (cvt_pk, register-only)
        float p[4][4];
#pragma unroll
        for (int nt = 0; nt < 4; nt++) {
            p[nt][0] = __expf(S[nt][0] - m_val);
            p[nt][1] = __expf(S[nt][1] - m_val);
            p[nt][2] = __expf(S[nt][2] - m_val);
            p[nt][3] = __expf(S[nt][3] - m_val);
            l_acc += (p[nt][0] + p[nt][1]) + (p[nt][2] + p[nt][3]);
        }
        uint32x4 U0, U1;
        U0[0] = cvtpk_bf16(p[0][0], p[0][1]);
        U0[1] = cvtpk_bf16(p[0][2], p[0][3]);
        U0[2] = cvtpk_bf16(p[1][0], p[1][1]);
        U0[3] = cvtpk_bf16(p[1][2], p[1][3]);
        U1[0] = cvtpk_bf16(p[2][0], p[2][1]);
        U1[1] = cvtpk_bf16(p[2][2], p[2][3]);
        U1[2] = cvtpk_bf16(p[3][0], p[3][1]);
        U1[3] = cvtpk_bf16(p[3][2], p[3][3]);
        bf16x8 w0 = __builtin_bit_cast(bf16x8, U0);
        bf16x8 w1 = __builtin_bit_cast(bf16x8, U1);

        // PV: V B-frags from LDS (row = c, swizzled), 2 MFMA per mt
        __builtin_amdgcn_s_setprio(1);
#pragma unroll
        for (int mt = 0; mt < 8; mt++) {
            const int vr = mt * 16 + col;
            bf16x8 v0 = *(const bf16x8*)(VtB + vr * 128 + ((q * 16) ^ swzv(vr)));
            bf16x8 v1 = *(const bf16x8*)(VtB + vr * 128 + ((64 + q * 16) ^ swzv(vr)));
            Oacc[mt] = __builtin_amdgcn_mfma_f32_16x16x32_bf16(v0, w0, Oacc[mt], 0, 0, 0);
            Oacc[mt] = __builtin_amdgcn_mfma_f32_16x16x32_bf16(v1, w1, Oacc[mt], 0, 0, 0);
        }
        __builtin_amdgcn_s_setprio(0);

        __syncthreads();   // buf ready-to-overwrite + next stage completed
        cur ^= 1;
    }
#undef STAGE

    // l partial: reduce across the 4 quad-groups; one atomic per row
    l_acc += __shfl_xor(l_acc, 16, 64);
    l_acc += __shfl_xor(l_acc, 32, 64);
    if (chg == 0 && q == 0)
        atomicAdd(Lbuf + (size_t)b * HW + i0g + iw, l_acc);

    // O partials: fp32 atomicAdd (js splits collide; chg disjoint)
    float* ob = out + (size_t)b * CV * HW;
#pragma unroll
    for (int mt = 0; mt < 8; mt++)
#pragma unroll
        for (int r = 0; r < 4; r++)
            atomicAdd(&ob[(size_t)(cbase + mt * 16 + q * 4 + r) * HW + i0g + iw],
                      Oacc[mt][r]);
}

// ---------------------------------------------------------------------------
// Kernel 3: out[b][c][i] /= L[b][i]
// ---------------------------------------------------------------------------
__global__ __launch_bounds__(256) void norm_out(
    float* __restrict__ out, const float* __restrict__ Lbuf)
{
    const int g    = blockIdx.x * 256 + threadIdx.x;   // float4 index
    const int flat = g * 4;
    const int i    = flat & (HW - 1);
    const int b    = flat >> 20;                       // / (CV*HW)
    float4 o = *(float4*)&out[flat];
    const float4 l4 = *(const float4*)&Lbuf[(size_t)b * HW + i];
    o.x /= l4.x; o.y /= l4.y; o.z /= l4.z; o.w /= l4.w;
    *(float4*)&out[flat] = o;
}

// ---------------------------------------------------------------------------
extern "C" void kernel_launch(void* const* d_in, const int* in_sizes, int n_in,
                              void* d_out, int out_size, void* d_ws, size_t ws_size,
                              hipStream_t stream)
{
    const float* x     = (const float*)d_in[0];
    const float* Wk    = (const float*)d_in[1];
    const float* bk    = (const float*)d_in[2];
    const float* gamma = (const float*)d_in[3];
    const float* beta  = (const float*)d_in[4];
    const float* mean  = (const float*)d_in[5];
    const float* var   = (const float*)d_in[6];
    const float* Wv    = (const float*)d_in[7];
    const float* bv    = (const float*)d_in[8];
    float* out = (float*)d_out;

    ushort*   Kbuf = (ushort*)d_ws;                          // [B][HW][CK]  2 MB
    ushort*   Vbuf = Kbuf + (size_t)B * HW * CK;             // [B][CV][HW]  8.4 MB
    ushort*   Wq   = Vbuf + (size_t)B * CV * HW;             // [320][256] packed, 160 KB
    float*    bq   = (float*)(Wq + (size_t)CO * C);          // [320]
    float*    mb   = bq + CO;                                // [B][HW]
    float*    Lbuf = mb + (size_t)B * HW;                    // [B][HW]
    unsigned* Mx   = (unsigned*)(Lbuf + (size_t)B * HW);     // [B]

    hipMemsetAsync(Lbuf, 0, (size_t)B * HW * sizeof(float), stream);
    hipMemsetAsync(out, 0, (size_t)out_size * sizeof(float), stream);

    wprep<<<dim3(CO), 256, 0, stream>>>(Wk, bk, gamma, beta, mean, var, Wv, bv, Wq, bq, Mx);

    kv_gemm<<<dim3(HW / 32, B), 256, 0, stream>>>(x, Wq, bq, Kbuf, Vbuf, mb, Mx);

    dim3 g2(HW / 64, CHG * JS, B);                           // (64,4,4) = 1024 blocks
    attn_kernel<<<g2, 256, 0, stream>>>(Kbuf, Vbuf, mb, Mx, out, Lbuf);

    norm_out<<<dim3(out_size / 4 / 256), 256, 0, stream>>>(out, Lbuf);
}

// Round 15
// 171.076 us; speedup vs baseline: 1.1523x; 1.1523x over previous
//
#include <hip/hip_runtime.h>
#include <math.h>

#define BN_EPS 1e-5f

constexpr int B  = 4;
constexpr int C  = 256;
constexpr int HW = 4096;   // 64*64
constexpr int CK = 64;
constexpr int CV = 256;
constexpr int CO = 320;    // CK + CV
constexpr int CHG = 2;     // channel groups in attn (128 ch each)

typedef short bf16x8 __attribute__((ext_vector_type(8)));
typedef float f32x4  __attribute__((ext_vector_type(4)));
typedef unsigned uint32x4 __attribute__((ext_vector_type(4)));

__device__ __forceinline__ ushort f2bf(float f) {
    unsigned u = __float_as_uint(f);
    u += 0x7FFFu + ((u >> 16) & 1u);      // round to nearest even
    return (ushort)(u >> 16);
}

// packed f32x2 -> bf16x2 (RNE), one VALU inst (T12 primitive)
__device__ __forceinline__ unsigned cvtpk_bf16(float lo, float hi) {
    unsigned r;
    asm("v_cvt_pk_bf16_f32 %0, %1, %2" : "=v"(r) : "v"(lo), "v"(hi));
    return r;
}

// byte-XOR swizzles (applied identically to pre-swizzled global source and
// LDS read -> involution, bijective within each 128-B row)
__device__ __forceinline__ int swzk(int r) {
    return (((r & 3) | ((((r >> 2) ^ (r >> 3)) & 1) << 2)) << 4);
}
__device__ __forceinline__ int swzv(int r) { return (r & 7) << 4; }

__device__ __forceinline__ void gload_lds16(const void* g, void* l) {
    __builtin_amdgcn_global_load_lds(
        (const __attribute__((address_space(1))) unsigned*)g,
        (__attribute__((address_space(3))) unsigned*)l, 16, 0, 0);
}

// ---------------------------------------------------------------------------
// Kernel 0: fold BN into Wk (row-scale), emit bf16 weights PRE-PACKED in
// kv_gemm's MFMA fragment order. Also zero-inits Mx (drops one memset
// dispatch; wprep precedes kv_gemm's atomicMax in-stream).
// ---------------------------------------------------------------------------
__global__ __launch_bounds__(256) void wprep(
    const float* __restrict__ Wk, const float* __restrict__ bk,
    const float* __restrict__ gamma, const float* __restrict__ beta,
    const float* __restrict__ mean,  const float* __restrict__ var,
    const float* __restrict__ Wv, const float* __restrict__ bv,
    ushort* __restrict__ Wq, float* __restrict__ bq, unsigned* __restrict__ Mx)
{
    const int co = blockIdx.x;
    const int c  = threadIdx.x;
    if (co < B && c == 0) Mx[co] = 0u;
    float w;
    if (co < CK) {
        float inv = gamma[co] * rsqrtf(var[co] + BN_EPS);
        w = Wk[co * C + c] * inv;
        if (c == 0) bq[co] = bk[co] * inv + (beta[co] - mean[co] * inv);
    } else {
        w = Wv[(co - CK) * C + c];
        if (c == 0) bq[co] = bv[co - CK];
    }
    // co = wv*80 + mi*16 + col ; c = ks*32 + q*8 + e
    const int wv  = co / 80, rem = co % 80;
    const int mi  = rem / 16, colw = rem % 16;
    const int ks  = c >> 5, qw = (c >> 3) & 3, e = c & 7;
    Wq[((((((wv * 8 + ks) * 5 + mi) * 4 + qw) * 16 + colw)) << 3) + e] = f2bf(w);
}

// ---------------------------------------------------------------------------
// Kernel 1: KV projection as MFMA GEMM + fused K-norms. UNCHANGED from R13
// (passed; kv_gemm proven non-dominant — four variants, identical e2e).
// ---------------------------------------------------------------------------
__global__ __launch_bounds__(256) void kv_gemm(
    const float* __restrict__ x, const ushort* __restrict__ Wq,
    const float* __restrict__ bq,
    ushort* __restrict__ Kbuf, ushort* __restrict__ Vbuf,
    float* __restrict__ mb, unsigned* __restrict__ Mx)
{
    __shared__ __align__(16) ushort xt[32][C + 8];   // [hw][c] bf16, pad 8

    const int t    = threadIdx.x;
    const int lane = t & 63;
    const int wv   = t >> 6;
    const int q    = lane >> 4;
    const int col  = lane & 15;
    const int hw0  = blockIdx.x * 32;
    const int b    = blockIdx.y;

    const float* xb = x + (size_t)b * C * HW;

    // stage x tile: strided dword loads -> pack bf16x4 -> b64 LDS write
    {
        const int cq  = (t >> 5) * 4;    // 0,4,...,28
        const int hwo = t & 31;
#pragma unroll
        for (int pass = 0; pass < 8; pass++) {
            const int c0 = pass * 32;
            float a0 = xb[(size_t)(c0 + cq + 0) * HW + hw0 + hwo];
            float a1 = xb[(size_t)(c0 + cq + 1) * HW + hw0 + hwo];
            float a2 = xb[(size_t)(c0 + cq + 2) * HW + hw0 + hwo];
            float a3 = xb[(size_t)(c0 + cq + 3) * HW + hw0 + hwo];
            ushort4 u = make_ushort4(f2bf(a0), f2bf(a1), f2bf(a2), f2bf(a3));
            *(ushort4*)&xt[hwo][c0 + cq] = u;
        }
    }
    __syncthreads();

    f32x4 acc[5][2];
#pragma unroll
    for (int mi = 0; mi < 5; mi++)
#pragma unroll
        for (int nt = 0; nt < 2; nt++)
            acc[mi][nt] = (f32x4){0.f, 0.f, 0.f, 0.f};

#pragma unroll
    for (int ks = 0; ks < 8; ks++) {
        bf16x8 av[5], bvv[2];
#pragma unroll
        for (int mi = 0; mi < 5; mi++)
            av[mi] = *(const bf16x8*)(Wq + ((size_t)((wv * 8 + ks) * 5 + mi) << 9) + lane * 8);
#pragma unroll
        for (int nt = 0; nt < 2; nt++)
            bvv[nt] = *(const bf16x8*)&xt[nt * 16 + col][ks * 32 + q * 8];
#pragma unroll
        for (int mi = 0; mi < 5; mi++)
#pragma unroll
            for (int nt = 0; nt < 2; nt++)
                acc[mi][nt] = __builtin_amdgcn_mfma_f32_16x16x32_bf16(bvv[nt], av[mi], acc[mi][nt], 0, 0, 0);
    }

    // D: row m = q*4+r -> hw = hw0 + nt*16 + q*4 + r ; col n -> co = cot+col
    float ssq[2][4] = {{0.f,0.f,0.f,0.f},{0.f,0.f,0.f,0.f}};
#pragma unroll
    for (int mi = 0; mi < 5; mi++) {
        const int cot = wv * 80 + mi * 16;
        const float bi = bq[cot + col];
#pragma unroll
        for (int nt = 0; nt < 2; nt++) {
            const int hwr = hw0 + nt * 16 + q * 4;
            float v0 = acc[mi][nt][0] + bi;
            float v1 = acc[mi][nt][1] + bi;
            float v2 = acc[mi][nt][2] + bi;
            float v3 = acc[mi][nt][3] + bi;
            if (cot < CK) {           // K: [hw][ck] layout, scalar stores
                const int ck = cot + col;
                Kbuf[((size_t)b * HW + hwr + 0) * CK + ck] = f2bf(v0);
                Kbuf[((size_t)b * HW + hwr + 1) * CK + ck] = f2bf(v1);
                Kbuf[((size_t)b * HW + hwr + 2) * CK + ck] = f2bf(v2);
                Kbuf[((size_t)b * HW + hwr + 3) * CK + ck] = f2bf(v3);
                ssq[nt][0] += v0 * v0; ssq[nt][1] += v1 * v1;
                ssq[nt][2] += v2 * v2; ssq[nt][3] += v3 * v3;
            } else {                  // V: [cv][hw] layout, ushort4 store
                const int cv = cot - CK + col;
                ushort4 vv = make_ushort4(f2bf(v0), f2bf(v1), f2bf(v2), f2bf(v3));
                *(ushort4*)&Vbuf[((size_t)b * CV + cv) * HW + hwr] = vv;
            }
        }
    }

    if (wv == 0) {   // wave 0 computed all K tiles: finish row norms
        float mxn = 0.f;
#pragma unroll
        for (int nt = 0; nt < 2; nt++) {
#pragma unroll
            for (int off = 1; off <= 8; off <<= 1)
#pragma unroll
                for (int r = 0; r < 4; r++)
                    ssq[nt][r] += __shfl_xor(ssq[nt][r], off, 64);
            float4 nr = make_float4(sqrtf(ssq[nt][0]), sqrtf(ssq[nt][1]),
                                    sqrtf(ssq[nt][2]), sqrtf(ssq[nt][3]));
            if (col == 0)
                *(float4*)&mb[(size_t)b * HW + hw0 + nt * 16 + q * 4] = nr;
            mxn = fmaxf(mxn, fmaxf(fmaxf(nr.x, nr.y), fmaxf(nr.z, nr.w)));
        }
#pragma unroll
        for (int off = 1; off <= 32; off <<= 1)
            mxn = fmaxf(mxn, __shfl_xor(mxn, off, 64));
        if (t == 0) atomicMax(Mx + b, __float_as_uint(mxn));
    }
}

// ---------------------------------------------------------------------------
// Kernel 2: MFMA flash attention. FINAL = R15 (best verified: attn 82.0 us,
// e2e 171.9 us). Zero-P-exchange fragment algebra (lane's S output IS its
// PV B-fragment), global_load_lds staging with swizzled conflict-free
// ds_read, double-buffer + 1 barrier/tile, cvt_pk P-packing, single-writer
// epilogue with fused 1/l.
//
// Session evidence for why this is the practical floor of the structure:
//   R11/R14: LDS traffic x2-x4 -> time invariant
//   R12/R18: TLP down OR up -> both regress (epilogue/residency costs)
//   R15: VALU -15% -> -4.4% (proportional, small)
//   R16: counted vmcnt vs drain -> null
//   R17: cross-tile SW pipeline -> -8%
// Remaining gap to pipes is dependency-latency at 2 waves/SIMD that no
// tested source-level structure converts; non-attn residual (~90 us) is
// fixed harness/launch overhead (4 kv_gemm variants identical).
// ---------------------------------------------------------------------------
__global__ __launch_bounds__(256, 2) void attn_kernel(
    const ushort* __restrict__ Kbuf, const ushort* __restrict__ Vbuf,
    const float* __restrict__ mb, const unsigned* __restrict__ Mx,
    float* __restrict__ out)
{
    __shared__ __align__(16) ushort Kt[2][64 * 64];    // 8 KB per buf
    __shared__ __align__(16) ushort Vt[2][128 * 64];   // 16 KB per buf

    const int t    = threadIdx.x;
    const int lane = t & 63;
    const int wv   = t >> 6;          // 0..3 : i-group within block
    const int q    = lane >> 4;       // quad 0..3
    const int col  = lane & 15;

    // --- XCD-partition remap (bijective on the 512-block grid) ---
    const unsigned lin = blockIdx.x + 64u * (blockIdx.y + (unsigned)CHG * blockIdx.z);
    const int xcd   = lin & 7;
    const int s_    = lin >> 3;              // 0..63
    const int i0g   = s_ * 64;
    const int chg   = xcd & 1;
    const int b     = xcd >> 1;              // 0..3

    const int iw    = wv * 16 + col;         // local i row (0..63)
    const int jperm = (col >> 2) * 8 + (col & 3);  // j-row permutation base

    const ushort* Kb = Kbuf + (size_t)b * HW * CK;
    const ushort* Vb = Vbuf + (size_t)b * CV * HW;
    const int cbase = chg * 128;

    // Q B-frags: B[k=ck][n=i], n = col -> i = i0g + iw (one-time scattered)
    bf16x8 qa[2];
#pragma unroll
    for (int k = 0; k < 2; k++)
        qa[k] = *(const bf16x8*)(Kb + (size_t)(i0g + iw) * CK + k * 32 + q * 8);

    // per-row exp bound (Cauchy-Schwarz): one scalar per lane
    const float Mxf = __uint_as_float(Mx[b]);
    const float m_val = mb[(size_t)b * HW + i0g + iw] * Mxf;

    f32x4 Oacc[8];
#pragma unroll
    for (int mt = 0; mt < 8; mt++)
        Oacc[mt] = (f32x4){0.f, 0.f, 0.f, 0.f};

    float l_acc = 0.f;
    const f32x4 zf = (f32x4){0.f, 0.f, 0.f, 0.f};

    // ---- staging: K tile 8 KB (2 chunks/wave), V tile 16 KB (4 chunks/wave)
    // LDS dest linear (rule 21); global source pre-swizzled.
#define STAGE(BUF, JN)                                                         \
    {                                                                          \
        const int jn_s = (JN);                                                 \
        _Pragma("unroll")                                                      \
        for (int p = 0; p < 2; p++) {                                          \
            int off = (wv * 2 + p) * 1024 + lane * 16;                         \
            int r = off >> 7, cb = off & 127;                                  \
            const char* g = (const char*)Kb + (size_t)(jn_s + r) * 128         \
                            + (cb ^ swzk(r));                                  \
            gload_lds16(g, (char*)&Kt[BUF][0] + off);                          \
        }                                                                      \
        _Pragma("unroll")                                                      \
        for (int p = 0; p < 4; p++) {                                          \
            int off = (wv * 4 + p) * 1024 + lane * 16;                         \
            int r = off >> 7, cb = off & 127;                                  \
            const char* g = (const char*)Vb                                    \
                            + ((size_t)(cbase + r) * HW + jn_s) * 2            \
                            + (cb ^ swzv(r));                                  \
            gload_lds16(g, (char*)&Vt[BUF][0] + off);                          \
        }                                                                      \
    }

    // prologue: stage tile 0 into buf 0
    STAGE(0, 0);
    __syncthreads();

    int cur = 0;
    for (int j0 = 0; j0 < HW; j0 += 64) {
        // issue next tile's staging first (full-tile latency window)
        STAGE(cur ^ 1, (j0 + 64) & (HW - 1));

        const char* KtB = (const char*)&Kt[cur][0];
        const char* VtB = (const char*)&Vt[cur][0];

        // S^T = mfma(K, Q): K A-frags from LDS (jperm rows, swizzled)
        f32x4 S[4];
        __builtin_amdgcn_s_setprio(1);
#pragma unroll
        for (int nt = 0; nt < 4; nt++) {
            const int jr = jperm + (nt >> 1) * 32 + (nt & 1) * 4;
            bf16x8 k0 = *(const bf16x8*)(KtB + jr * 128 + ((q * 16) ^ swzk(jr)));
            bf16x8 k1 = *(const bf16x8*)(KtB + jr * 128 + ((64 + q * 16) ^ swzk(jr)));
            S[nt] = __builtin_amdgcn_mfma_f32_16x16x32_bf16(k0, qa[0], zf, 0, 0, 0);
            S[nt] = __builtin_amdgcn_mfma_f32_16x16x32_bf16(k1, qa[1], S[nt], 0, 0, 0);
        }
        __builtin_amdgcn_s_setprio(0);

        // exp + pack into PV B-fragments: v_cvt_pk_bf16_f32 (2 f32 -> 1
        // dword, RNE) -> uint32x4 -> bit_cast to bf16x8.
        float p[4][4];
#pragma unroll
        for (int nt = 0; nt < 4; nt++) {
            p[nt][0] = __expf(S[nt][0] - m_val);
            p[nt][1] = __expf(S[nt][1] - m_val);
            p[nt][2] = __expf(S[nt][2] - m_val);
            p[nt][3] = __expf(S[nt][3] - m_val);
            l_acc += (p[nt][0] + p[nt][1]) + (p[nt][2] + p[nt][3]);
        }
        uint32x4 U0, U1;
        U0[0] = cvtpk_bf16(p[0][0], p[0][1]);
        U0[1] = cvtpk_bf16(p[0][2], p[0][3]);
        U0[2] = cvtpk_bf16(p[1][0], p[1][1]);
        U0[3] = cvtpk_bf16(p[1][2], p[1][3]);
        U1[0] = cvtpk_bf16(p[2][0], p[2][1]);
        U1[1] = cvtpk_bf16(p[2][2], p[2][3]);
        U1[2] = cvtpk_bf16(p[3][0], p[3][1]);
        U1[3] = cvtpk_bf16(p[3][2], p[3][3]);
        bf16x8 w0 = __builtin_bit_cast(bf16x8, U0);
        bf16x8 w1 = __builtin_bit_cast(bf16x8, U1);

        // PV: V B-frags from LDS (row = c, swizzled), 2 MFMA per mt
        __builtin_amdgcn_s_setprio(1);
#pragma unroll
        for (int mt = 0; mt < 8; mt++) {
            const int vr = mt * 16 + col;
            bf16x8 v0 = *(const bf16x8*)(VtB + vr * 128 + ((q * 16) ^ swzv(vr)));
            bf16x8 v1 = *(const bf16x8*)(VtB + vr * 128 + ((64 + q * 16) ^ swzv(vr)));
            Oacc[mt] = __builtin_amdgcn_mfma_f32_16x16x32_bf16(v0, w0, Oacc[mt], 0, 0, 0);
            Oacc[mt] = __builtin_amdgcn_mfma_f32_16x16x32_bf16(v1, w1, Oacc[mt], 0, 0, 0);
        }
        __builtin_amdgcn_s_setprio(0);

        __syncthreads();   // buf ready-to-overwrite + next stage completed
        cur ^= 1;
    }
#undef STAGE

    // row sum l for i = i0g+iw: reduce across the 4 quad-groups
    l_acc += __shfl_xor(l_acc, 16, 64);
    l_acc += __shfl_xor(l_acc, 32, 64);
    const float inv = 1.0f / l_acc;

    // O store (single-writer; chg disjoint): fused division
    float* ob = out + (size_t)b * CV * HW;
#pragma unroll
    for (int mt = 0; mt < 8; mt++)
#pragma unroll
        for (int r = 0; r < 4; r++)
            ob[(size_t)(cbase + mt * 16 + q * 4 + r) * HW + i0g + iw] = Oacc[mt][r] * inv;
}

// ---------------------------------------------------------------------------
extern "C" void kernel_launch(void* const* d_in, const int* in_sizes, int n_in,
                              void* d_out, int out_size, void* d_ws, size_t ws_size,
                              hipStream_t stream)
{
    const float* x     = (const float*)d_in[0];
    const float* Wk    = (const float*)d_in[1];
    const float* bk    = (const float*)d_in[2];
    const float* gamma = (const float*)d_in[3];
    const float* beta  = (const float*)d_in[4];
    const float* mean  = (const float*)d_in[5];
    const float* var   = (const float*)d_in[6];
    const float* Wv    = (const float*)d_in[7];
    const float* bv    = (const float*)d_in[8];
    float* out = (float*)d_out;

    ushort*   Kbuf = (ushort*)d_ws;                          // [B][HW][CK]  2 MB
    ushort*   Vbuf = Kbuf + (size_t)B * HW * CK;             // [B][CV][HW]  8.4 MB
    ushort*   Wq   = Vbuf + (size_t)B * CV * HW;             // [320][256] packed, 160 KB
    float*    bq   = (float*)(Wq + (size_t)CO * C);          // [320]
    float*    mb   = bq + CO;                                // [B][HW]
    unsigned* Mx   = (unsigned*)(mb + (size_t)B * HW);       // [B]

    wprep<<<dim3(CO), 256, 0, stream>>>(Wk, bk, gamma, beta, mean, var, Wv, bv, Wq, bq, Mx);

    kv_gemm<<<dim3(HW / 32, B), 256, 0, stream>>>(x, Wq, bq, Kbuf, Vbuf, mb, Mx);

    dim3 g2(HW / 64, CHG, B);                                // (64,2,4) = 512 blocks
    attn_kernel<<<g2, 256, 0, stream>>>(Kbuf, Vbuf, mb, Mx, out);
}